// Round 1
// 844.813 us; speedup vs baseline: 1.1760x; 1.1760x over previous
//
#include <hip/hip_runtime.h>
#include <cstdint>
#include <cstddef>

// GraphConvolution: out = (A_sparse @ x) @ W^T + b   (N=100000, E=3.2M, D=256)
// Pipeline: hist -> scan -> CSR scatter -> castX(bf16) -> gather (reg acc,
//           bf16 x in / bf16 agg out) -> bf16 MFMA GEMM (agg @ W^T + b).
// NOTE: never use the 2nd __launch_bounds__ arg here — R2/R3 showed it caps
// VGPRs to ~84 and forces ~2.3 GB of scratch spill traffic in the gather.
// R(this): x is cast to bf16 once (51 MB) so each edge moves 512B instead of
// 1KB through L1/L2/L3 fabric — gather was byte-bound on x rows, not VALU/HBM.
#define D 256
#define NPB 32
#define SCAN_CHUNK 2048

typedef __attribute__((ext_vector_type(8))) short short8;
typedef __attribute__((ext_vector_type(4))) float floatx4;

__device__ __forceinline__ unsigned short f2bf(float f) {
    union { float f; unsigned int u; } cv; cv.f = f;
    unsigned int u = cv.u;
    unsigned int r = (u + 0x7fffu + ((u >> 16) & 1u)) >> 16;  // RNE
    return (unsigned short)r;
}

__device__ __forceinline__ float bf2f(unsigned short s) {
    union { unsigned int u; float f; } cv;
    cv.u = ((unsigned int)s) << 16;
    return cv.f;
}

__global__ void k_hist(const int* __restrict__ erow, int* __restrict__ counts, int e) {
    int i = blockIdx.x * blockDim.x + threadIdx.x;
    if (i < e) atomicAdd(&counts[erow[i]], 1);
}

__global__ void k_scan1(const int* __restrict__ counts, int* __restrict__ row_start,
                        int* __restrict__ blk_sums, int n) {
    __shared__ int sd[256];
    int tid = threadIdx.x;
    int base = blockIdx.x * SCAN_CHUNK + tid * 8;
    int v[8];
    int s = 0;
#pragma unroll
    for (int i = 0; i < 8; ++i) {
        int idx = base + i;
        v[i] = (idx < n) ? counts[idx] : 0;
        s += v[i];
    }
    sd[tid] = s;
    __syncthreads();
    for (int off = 1; off < 256; off <<= 1) {
        int t = (tid >= off) ? sd[tid - off] : 0;
        __syncthreads();
        sd[tid] += t;
        __syncthreads();
    }
    int run = sd[tid] - s;
    if (tid == 255) blk_sums[blockIdx.x] = sd[255];
#pragma unroll
    for (int i = 0; i < 8; ++i) {
        int idx = base + i;
        if (idx < n) row_start[idx] = run;
        run += v[i];
    }
}

__global__ void k_scan2(int* __restrict__ blk_sums, int* __restrict__ row_start, int nch, int n) {
    __shared__ int sd[64];
    int tid = threadIdx.x;
    if (tid < nch) sd[tid] = blk_sums[tid];
    __syncthreads();
    if (tid == 0) {
        int run = 0;
        for (int b = 0; b < nch; ++b) { int t = sd[b]; sd[b] = run; run += t; }
        row_start[n] = run;
    }
    __syncthreads();
    if (tid < nch) blk_sums[tid] = sd[tid];
}

__global__ void k_scan3(int* __restrict__ row_start, const int* __restrict__ blk_sums, int n) {
    int i = blockIdx.x * blockDim.x + threadIdx.x;
    if (i < n) row_start[i] += blk_sums[i >> 11];
}

__global__ void k_scatter(const int* __restrict__ erow, const int* __restrict__ ecol,
                          const float* __restrict__ eval, const int* __restrict__ row_start,
                          int* __restrict__ cursor, int2* __restrict__ sedge, int e) {
    int i = blockIdx.x * blockDim.x + threadIdx.x;
    if (i < e) {
        int r = erow[i];
        int p = row_start[r] + atomicAdd(&cursor[r], 1);
        sedge[p] = make_int2(ecol[i], __float_as_int(eval[i]));
    }
}

__global__ void k_castW(const float* __restrict__ W, unsigned short* __restrict__ Wb) {
    int i = blockIdx.x * blockDim.x + threadIdx.x;  // 65536
    Wb[i] = f2bf(W[i]);
}

// Cast x (fp32, 102 MB) -> bf16 (51 MB). One-shot streaming kernel, ~25us.
__global__ void k_castX(const float* __restrict__ x, unsigned short* __restrict__ xb) {
    size_t i = ((size_t)blockIdx.x * blockDim.x + threadIdx.x) * 8;
    float4 a = *(const float4*)&x[i];
    float4 b = *(const float4*)&x[i + 4];
    short8 v;
    v[0] = (short)f2bf(a.x); v[1] = (short)f2bf(a.y);
    v[2] = (short)f2bf(a.z); v[3] = (short)f2bf(a.w);
    v[4] = (short)f2bf(b.x); v[5] = (short)f2bf(b.y);
    v[6] = (short)f2bf(b.z); v[7] = (short)f2bf(b.w);
    *(short8*)&xb[i] = v;
}

// Gather: each wave owns 8 nodes IN PARALLEL (8 independent load chains per
// iteration = MLP). No LDS, register accumulators, bf16 x rows (512B/edge),
// bf16 output rows. Accumulation in fp32.
__global__ __launch_bounds__(256) void k_gather(
    const unsigned short* __restrict__ xb, const int2* __restrict__ sedge,
    const int* __restrict__ row_start, unsigned short* __restrict__ aggb, int n) {
    const int tid = threadIdx.x;
    const int lane = tid & 63;
    const int wv = tid >> 6;
    const int base_node = blockIdx.x * NPB + wv * 8;

    int ebeg[8], eend[8];
    int maxd = 0;
#pragma unroll
    for (int j = 0; j < 8; ++j) {
        ebeg[j] = row_start[base_node + j];
        eend[j] = row_start[base_node + j + 1];
        maxd = max(maxd, eend[j] - ebeg[j]);
    }
    float4 acc[8];
#pragma unroll
    for (int j = 0; j < 8; ++j) acc[j] = make_float4(0.f, 0.f, 0.f, 0.f);

    for (int it = 0; it < maxd; ++it) {
        int2 ev[8];
        ushort4 xv[8];
#pragma unroll
        for (int j = 0; j < 8; ++j) {
            int e = ebeg[j] + it;
            int ec = max(min(e, eend[j] - 1), 0);  // clamped: always valid
            ev[j] = sedge[ec];
        }
#pragma unroll
        for (int j = 0; j < 8; ++j) {
            // 8B/lane, 512B/wave coalesced bf16 row slice
            xv[j] = *(const ushort4*)&xb[(size_t)ev[j].x * D + lane * 4];
        }
#pragma unroll
        for (int j = 0; j < 8; ++j) {
            float v = (ebeg[j] + it < eend[j]) ? __int_as_float(ev[j].y) : 0.f;
            acc[j].x += v * bf2f(xv[j].x);
            acc[j].y += v * bf2f(xv[j].y);
            acc[j].z += v * bf2f(xv[j].z);
            acc[j].w += v * bf2f(xv[j].w);
        }
    }
#pragma unroll
    for (int j = 0; j < 8; ++j) {
        ushort4 u;
        u.x = f2bf(acc[j].x);
        u.y = f2bf(acc[j].y);
        u.z = f2bf(acc[j].z);
        u.w = f2bf(acc[j].w);
        *(ushort4*)&aggb[(size_t)(base_node + j) * D + lane * 4] = u;  // 512B/row
    }
}

// GEMM: out[m][o] = sum_k aggb[m][k] * Wb[o][k] + bias[o], bf16 MFMA.
// Block = 4 waves x 16 rows = 64-row M-tile, full N=256, K chunked by 64.
// A-frag: A[m=lane&15][k=quad*8+j]; B-frag: B[k=quad*8+j][n=lane&15] with
// B[k][n] = W[n][k] (16B contiguous from row-major W). C/D: col=lane&15,
// row=quad*4+reg (m89-verified). LDS W rows padded to 72 bf16 -> balanced banks.
__global__ __launch_bounds__(256) void k_gemm(
    const unsigned short* __restrict__ aggb, const unsigned short* __restrict__ Wb,
    const float* __restrict__ bias, float* __restrict__ out, int M) {
    __shared__ __align__(16) unsigned short Wl[256 * 72];  // 36 KB

    const int tid = threadIdx.x;
    const int lane = tid & 63;
    const int wv = tid >> 6;
    const int col = lane & 15;
    const int quad = lane >> 4;
    const int bm = blockIdx.x * 64 + wv * 16;

    floatx4 acc[16];
#pragma unroll
    for (int i = 0; i < 16; ++i) acc[i] = (floatx4){0.f, 0.f, 0.f, 0.f};

    const int arow = min(bm + col, M - 1);  // clamp (stores are guarded)

    for (int kc = 0; kc < 4; ++kc) {
        __syncthreads();
        // stage W[0..255][kc*64 .. +63] -> Wl, thread t = row t (8x 16B)
        {
            const uint4* src = (const uint4*)(Wb + (size_t)tid * D + kc * 64);
#pragma unroll
            for (int s = 0; s < 8; ++s) {
                *(uint4*)&Wl[tid * 72 + s * 8] = src[s];
            }
        }
        __syncthreads();

        short8 a[2];
#pragma unroll
        for (int t2 = 0; t2 < 2; ++t2) {
            a[t2] = *(const short8*)&aggb[(size_t)arow * D + kc * 64 + t2 * 32 + quad * 8];
        }
#pragma unroll
        for (int i = 0; i < 16; ++i) {
#pragma unroll
            for (int t2 = 0; t2 < 2; ++t2) {
                short8 b = *(const short8*)&Wl[(i * 16 + col) * 72 + t2 * 32 + quad * 8];
                acc[i] = __builtin_amdgcn_mfma_f32_16x16x32_bf16(a[t2], b, acc[i], 0, 0, 0);
            }
        }
    }

#pragma unroll
    for (int i = 0; i < 16; ++i) {
        int o = i * 16 + col;
        float bv = bias[o];
#pragma unroll
        for (int r = 0; r < 4; ++r) {
            int m = bm + quad * 4 + r;
            if (m < M) out[(size_t)m * D + o] = acc[i][r] + bv;
        }
    }
}

extern "C" void kernel_launch(void* const* d_in, const int* in_sizes, int n_in,
                              void* d_out, int out_size, void* d_ws, size_t ws_size,
                              hipStream_t stream) {
    const float* x    = (const float*)d_in[0];
    const int*   erow = (const int*)d_in[1];
    const int*   ecol = (const int*)d_in[2];
    const float* eval = (const float*)d_in[3];
    const float* W    = (const float*)d_in[4];
    const float* bias = (const float*)d_in[5];
    float* out = (float*)d_out;

    const int n = in_sizes[0] / D;  // 100000
    const int e = in_sizes[1];      // 3200000

    // ws: counts[n] | cursor[n] | blk_sums[64] | row_start[n+1] | sedge[e] int2
    //     | Wb[65536] u16 | aggb[n*256] u16 | xb[n*256] u16   (~130 MB total)
    int* counts    = (int*)d_ws;
    int* cursor    = counts + n;
    int* blk_sums  = cursor + n;
    int* row_start = blk_sums + 64;
    int2* sedge    = (int2*)(((uintptr_t)(row_start + n + 1) + 15) & ~(uintptr_t)15);
    unsigned short* Wb   = (unsigned short*)(sedge + e);
    unsigned short* aggb = Wb + 65536;
    unsigned short* xb   = aggb + (size_t)n * D;

    hipMemsetAsync(counts, 0, (size_t)(2 * n + 64) * sizeof(int), stream);

    const int nch = (n + SCAN_CHUNK - 1) / SCAN_CHUNK;  // 49

    k_hist<<<(e + 255) / 256, 256, 0, stream>>>(erow, counts, e);
    k_scan1<<<nch, 256, 0, stream>>>(counts, row_start, blk_sums, n);
    k_scan2<<<1, 64, 0, stream>>>(blk_sums, row_start, nch, n);
    k_scan3<<<(n + 255) / 256, 256, 0, stream>>>(row_start, blk_sums, n);
    k_castW<<<256, 256, 0, stream>>>(W, Wb);
    k_castX<<<(n * D / 8 + 255) / 256, 256, 0, stream>>>(x, xb);
    k_scatter<<<(e + 255) / 256, 256, 0, stream>>>(erow, ecol, eval, row_start, cursor, sedge, e);
    k_gather<<<n / NPB, 256, 0, stream>>>(xb, sedge, row_start, aggb, n);
    k_gemm<<<(n + 63) / 64, 256, 0, stream>>>(aggb, Wb, bias, out, n);
}